// Round 9
// baseline (74.278 us; speedup 1.0000x reference)
//
#include <hip/hip_runtime.h>

typedef unsigned long long u64;
typedef unsigned int u32;

#define NBOX 8192
#define NW64 128    // u64 words per fallback suppression bitmap
#define NCLASS 80
#define MAXC 512    // clist capacity per class
#define NCMAX 256   // fast-path class size cap; nc>NCMAX flags exact fallback
#define CHKCAP 256
#define NS 16       // rank slices
#define SLICE 512   // NBOX / NS
#define NBLK 32     // rank blocks per slice

// ---- monotone float<->uint mapping (order-preserving for all floats) ----
__device__ __forceinline__ u32 f32_mono(float f) {
  u32 u = __float_as_uint(f);
  return (u & 0x80000000u) ? ~u : (u | 0x80000000u);
}
__device__ __forceinline__ float mono_f32(u32 u) {
  u32 b = (u & 0x80000000u) ? (u ^ 0x80000000u) : ~u;
  return __uint_as_float(b);
}
__device__ __forceinline__ float readlane_f(float v, int l) {
  return __uint_as_float(__builtin_amdgcn_readlane(__float_as_uint(v), l));
}
// reduce 32-entry u32 array of block maxima, in-register
__device__ __forceinline__ u32 reduce_bmax(const u32* __restrict__ bmax, int t) {
  u32 bm = bmax[t & 31];
#pragma unroll
  for (int off = 16; off > 0; off >>= 1) {
    u32 o = __shfl_xor(bm, off);
    bm = (bm > o) ? bm : o;
  }
  return bm;
}

// NOTE (r7/r8 lesson): in-kernel grid barriers are a dead end on gfx950 —
// RMW-polling convoys the coherence point (~27us/barrier, r7) and even
// load-polling still needs __threadfence release/acquire, whose
// buffer_wbl2/buffer_inv L2 walk costs ~20us/barrier (r8: 55us tail,
// FETCH_SIZE == working set refetched). Kernel boundaries provide the same
// coherence cheaper. Hence: 3 plain kernels, no fences, no barriers.

// ---- K1: rank-by-enumeration + box decode/block-max (slice 0) + ws init.
// Rank key: (~mono(score) << 32) | (idx << 8) | cls.
// Ascending key == (score desc, idx asc); cls rides in low 8 bits only for
// the free class-equality test (idx uniqueness keeps ordering exact).
__global__ __launch_bounds__(256) void rank_decode_kernel(
    const float* __restrict__ scores, const int* __restrict__ class_ids,
    const float4* __restrict__ deltas, const float2* __restrict__ locs,
    const int* __restrict__ stride_p, float4* __restrict__ boxes_out,
    u32* __restrict__ bmax, int* __restrict__ flag, int* __restrict__ ccount,
    int* __restrict__ rankp, int* __restrict__ rcp) {
  int t = threadIdx.x;
  int i = blockIdx.x * 256 + t;
  int slice = blockIdx.y;

  __shared__ u64 kt[SLICE];
  __shared__ u32 wmax[4];

  if (slice == 0) {  // decode boxes + block max + ws init (block-uniform)
    float s = (float)(*stride_p);
    float4 d = deltas[i];
    d.x = fmaxf(d.x, 0.f); d.y = fmaxf(d.y, 0.f);
    d.z = fmaxf(d.z, 0.f); d.w = fmaxf(d.w, 0.f);
    float2 c = locs[i];
    float4 b;
    b.x = c.x - s * d.x;
    b.y = c.y - s * d.y;
    b.z = c.x + s * d.z;
    b.w = c.y + s * d.w;
    boxes_out[i] = b;
    float m = fmaxf(fmaxf(b.x, b.y), fmaxf(b.z, b.w));
    u32 u = f32_mono(m);
#pragma unroll
    for (int off = 32; off > 0; off >>= 1) {
      u32 o = __shfl_xor(u, off);
      u = (u > o) ? u : o;
    }
    if ((t & 63) == 0) wmax[t >> 6] = u;
    __syncthreads();
    if (t == 0) {
      u32 m0 = wmax[0] > wmax[1] ? wmax[0] : wmax[1];
      u32 m1 = wmax[2] > wmax[3] ? wmax[2] : wmax[3];
      bmax[blockIdx.x] = m0 > m1 ? m0 : m1;  // plain store, no init needed
    }
    if (blockIdx.x == 0) {  // init for K2/K3 (kernel-boundary coherence)
      if (t == 0) *flag = 0;
      if (t < NCLASS) ccount[t] = 0;
    }
  }

  for (int p = t; p < SLICE; p += 256) {
    int j = slice * SLICE + p;
    u32 mj = f32_mono(scores[j]);
    kt[p] = ((u64)(~mj) << 32) | ((u32)j << 8) | (u32)(class_ids[j] & 0xff);
  }
  __syncthreads();

  u32 mi = f32_mono(scores[i]);
  u32 ci = (u32)(class_ids[i] & 0xff);
  u64 ki = ((u64)(~mi) << 32) | ((u32)i << 8) | ci;
  int cnt = 0, ccnt = 0;
#pragma unroll 8
  for (int p = 0; p < SLICE; ++p) {
    u64 kj = kt[p];  // wave-uniform LDS address -> broadcast
    bool less = kj < ki;
    bool ceq = (((u32)(kj ^ ki)) & 0xffu) == 0u;
    cnt += less ? 1 : 0;
    ccnt += (less && ceq) ? 1 : 0;
  }
  rankp[slice * NBOX + i] = cnt;
  rcp[slice * NBOX + i] = ccnt;
}

// ---- K2: scatter by rank (blocks 0..31) + cross-class hazard check (block
// 32). All flag sources (class overflow, hazard) finalize in this kernel.
__global__ __launch_bounds__(256) void scatter_hazard_kernel(
    const float* __restrict__ scores, const int* __restrict__ class_ids,
    const float4* __restrict__ boxes, const u32* __restrict__ bmax,
    const int* __restrict__ rankp, const int* __restrict__ rcp,
    u64* __restrict__ keys, float4* __restrict__ bnms,
    u32* __restrict__ clist, int* __restrict__ ccount,
    float* __restrict__ order_out, int* flag) {
  const int t = threadIdx.x;
  const int bid = blockIdx.x;

  if (bid < NBLK) {  // ---- scatter ----
    int i = bid * 256 + t;
    int r = 0, rc = 0;
#pragma unroll
    for (int s = 0; s < NS; ++s) {  // coalesced within each slice row
      r += rankp[s * NBOX + i];
      rc += rcp[s * NBOX + i];
    }
    float maxc = mono_f32(reduce_bmax(bmax, t));
    u32 mi = f32_mono(scores[i]);
    keys[r] = ((u64)(~mi) << 32) | (u32)i;  // clean key for fallback
    int cls = class_ids[i];
    float off = (float)cls * (maxc + 1.0f);
    float4 b = boxes[i];
    b.x += off; b.y += off; b.z += off; b.w += off;
    bnms[r] = b;
    order_out[r] = (float)i;
    if (rc < MAXC) clist[cls * MAXC + rc] = ((u32)i << 16) | (u32)r;
    if (rc >= NCMAX) atomicOr(flag, 1);  // class too big for fast path
    atomicAdd(&ccount[cls], 1);
    return;
  }

  // ---- hazard check (block 32): adjacent-class offset boxes can only
  // overlap if one box hugs the top-right margin (x2,y2 > M-65; x1,y1 >= -64
  // by construction) and the other the bottom-left margin (x1,y1 < 1).
  // Conservative IoU > 0.4 vs reference 0.5.
  __shared__ float4 bxA[CHKCAP], bxB[CHKCAP];
  __shared__ int clsA[CHKCAP], clsB[CHKCAP];
  __shared__ int na, nb;
  if (t == 0) { na = 0; nb = 0; }
  __syncthreads();
  float M = mono_f32(reduce_bmax(bmax, t));
  float thrA = M - 65.0f;
  for (int base = 0; base < NBOX; base += 256) {
    int ii = base + t;
    float4 bb = boxes[ii];
    int cls = class_ids[ii];
    if (bb.z > thrA && bb.w > thrA) {
      int p = atomicAdd(&na, 1);
      if (p < CHKCAP) { bxA[p] = bb; clsA[p] = cls; }
    }
    if (bb.x < 1.0f && bb.y < 1.0f) {
      int p = atomicAdd(&nb, 1);
      if (p < CHKCAP) { bxB[p] = bb; clsB[p] = cls; }
    }
  }
  __syncthreads();
  int NA = na < CHKCAP ? na : CHKCAP;
  int NB = nb < CHKCAP ? nb : CHKCAP;
  if (t == 0 && (na > CHKCAP || nb > CHKCAP)) atomicOr(flag, 1);
  bool hit = false;
  for (int pr = t; pr < NA * NB; pr += 256) {
    int a = pr / NB, b2 = pr % NB;
    if (clsB[b2] != clsA[a] + 1) continue;
    float offa = (float)clsA[a] * (M + 1.0f);
    float offb = (float)clsB[b2] * (M + 1.0f);
    float4 A = bxA[a], Bb = bxB[b2];
    A.x += offa; A.y += offa; A.z += offa; A.w += offa;
    Bb.x += offb; Bb.y += offb; Bb.z += offb; Bb.w += offb;
    float ltx = fmaxf(A.x, Bb.x), lty = fmaxf(A.y, Bb.y);
    float rbx = fminf(A.z, Bb.z), rby = fminf(A.w, Bb.w);
    float ww = fmaxf(rbx - ltx, 0.f), hh = fmaxf(rby - lty, 0.f);
    float inter = ww * hh;
    float aa = (A.z - A.x) * (A.w - A.y);
    float ab = (Bb.z - Bb.x) * (Bb.w - Bb.y);
    float iou = inter / (aa + ab - inter);
    if (iou > 0.4f) hit = true;
  }
  if (hit) atomicOr(flag, 1);
}

// ---- K3: per-class all-register NMS (blocks 0..79) + exact fallback
// (block 80, runs only when flag != 0). flag is finalized in K2 and
// read-only here, so fast-path blocks skip their writes when flag != 0 —
// no write race with the fallback block.
__global__ __launch_bounds__(256) void nms_kernel(
    const u32* __restrict__ clist, const int* __restrict__ ccount,
    const float4* __restrict__ bnms, const u64* __restrict__ keys,
    float* __restrict__ keep_out, const int* __restrict__ flag) {
  const int t = threadIdx.x;
  const int bid = blockIdx.x;
  const int fl = *flag;

  if (bid < NCLASS) {
    if (fl != 0 || t >= 64) return;  // fallback covers everything
    // lane t owns boxes t, t+64, t+128, t+192 of class bid; remv = 4
    // wave-uniform u64 (SGPR). Per kept row i: 4 readlanes broadcast box i,
    // <=4 IoU+ballot passes OR into remv. No LDS on the serial path.
    int c = bid;
    int nc = ccount[c];  // nc <= NCMAX guaranteed (else fl != 0)
    u32 L[4];
    float4 B[4];
#pragma unroll
    for (int d = 0; d < 4; ++d) {
      int j = d * 64 + t;
      L[d] = (j < nc) ? clist[c * MAXC + j] : 0u;
      B[d] = bnms[L[d] & 0xffffu];  // j>=nc -> harmless read of bnms[0]
    }
    u64 r0 = 0, r1 = 0, r2 = 0, r3 = 0;

#define CHUNK(CC, RC, PASSES)                                                  \
  {                                                                            \
    int lim = nc - CC * 64;                                                    \
    if (lim > 0) {                                                             \
      if (lim > 64) lim = 64;                                                  \
      for (int ii = 0; ii < lim; ++ii) {                                       \
        if (!((RC >> ii) & 1ull)) {                                            \
          float bix = readlane_f(B[CC].x, ii);                                 \
          float biy = readlane_f(B[CC].y, ii);                                 \
          float biz = readlane_f(B[CC].z, ii);                                 \
          float biw = readlane_f(B[CC].w, ii);                                 \
          float area_i = (biz - bix) * (biw - biy);                            \
          PASSES                                                               \
        }                                                                      \
      }                                                                        \
    }                                                                          \
  }
#define PASS(DD, RD, JGUARD)                                                   \
  {                                                                            \
    float4 bj = B[DD];                                                         \
    float ltx = fmaxf(bix, bj.x), lty = fmaxf(biy, bj.y);                      \
    float rbx = fminf(biz, bj.z), rby = fminf(biw, bj.w);                      \
    float ww = fmaxf(rbx - ltx, 0.f), hh = fmaxf(rby - lty, 0.f);              \
    float inter = ww * hh;                                                     \
    float area_j = (bj.z - bj.x) * (bj.w - bj.y);                              \
    float iou = inter / (area_i + area_j - inter);                             \
    int j = DD * 64 + t;                                                       \
    bool p = (iou > 0.5f) && (j < nc) && (JGUARD);                             \
    RD |= __ballot(p);                                                         \
  }

    CHUNK(0, r0, PASS(0, r0, t > ii) PASS(1, r1, true) PASS(2, r2, true) PASS(3, r3, true))
    CHUNK(1, r1, PASS(1, r1, t > ii) PASS(2, r2, true) PASS(3, r3, true))
    CHUNK(2, r2, PASS(2, r2, t > ii) PASS(3, r3, true))
    CHUNK(3, r3, PASS(3, r3, t > ii))
#undef PASS
#undef CHUNK

    u64 rr[4] = {r0, r1, r2, r3};
#pragma unroll
    for (int d = 0; d < 4; ++d) {
      int j = d * 64 + t;
      if (j < nc) keep_out[L[d] >> 16] = ((rr[d] >> t) & 1ull) ? 0.0f : 1.0f;
    }
    return;
  }

  // ---- block 80: exact single-block fallback (flag != 0 only) ----
  if (fl == 0) return;
  __shared__ u64 remv[NW64];
  for (int k = t; k < NW64; k += 256) remv[k] = 0;
  __syncthreads();
  if (t < 64) {
    int lane = t;
    for (int ii = 0; ii < NBOX; ++ii) {
      if ((remv[ii >> 6] >> (ii & 63)) & 1ull) continue;
      float4 bi = bnms[ii];
      float area_i = (bi.z - bi.x) * (bi.w - bi.y);
      for (int jb = ii + 1; jb < NBOX; jb += 64) {
        int j = jb + lane;
        bool p = false;
        if (j < NBOX) {
          float4 bj = bnms[j];
          float ltx = fmaxf(bi.x, bj.x), lty = fmaxf(bi.y, bj.y);
          float rbx = fminf(bi.z, bj.z), rby = fminf(bi.w, bj.w);
          float ww = fmaxf(rbx - ltx, 0.f), hh = fmaxf(rby - lty, 0.f);
          float inter = ww * hh;
          float area_j = (bj.z - bj.x) * (bj.w - bj.y);
          float iou = inter / (area_i + area_j - inter);
          p = iou > 0.5f;
        }
        u64 m = __ballot(p);
        if (lane == 0 && m) {
          int w0 = jb >> 6, sh = jb & 63;
          remv[w0] |= (m << sh);
          if (sh && (w0 + 1) < NW64) remv[w0 + 1] |= (m >> (64 - sh));
        }
      }
    }
  }
  __syncthreads();
  for (int k = t; k < NBOX; k += 256)
    keep_out[(u32)keys[k]] = ((remv[k >> 6] >> (k & 63)) & 1ull) ? 0.0f : 1.0f;
}

extern "C" void kernel_launch(void* const* d_in, const int* in_sizes, int n_in,
                              void* d_out, int out_size, void* d_ws, size_t ws_size,
                              hipStream_t stream) {
  const float* deltas = (const float*)d_in[0];
  const float* locs = (const float*)d_in[1];
  const float* scores = (const float*)d_in[2];
  const int* class_ids = (const int*)d_in[3];
  const int* stride_p = (const int*)d_in[4];

  float* boxes_out = (float*)d_out;                     // n*4 floats
  float* keep_out = (float*)d_out + (size_t)NBOX * 4;   // n floats (0/1)
  float* order_out = (float*)d_out + (size_t)NBOX * 5;  // n floats (indices)

  // workspace layout (all init done in-kernel; no memset nodes)
  u32* bmax = (u32*)((char*)d_ws + 64);           // 32*4 B, plain-stored
  int* flag = (int*)((char*)d_ws + 256);          // init'd by K1
  int* ccount = (int*)((char*)d_ws + 512);        // 80*4 B, init'd by K1
  u64* keys = (u64*)((char*)d_ws + 4096);         // 64 KiB
  float4* bnms = (float4*)((char*)d_ws + 4096 + 65536);  // 128 KiB
  char* base2 = (char*)d_ws + 4096 + 65536 + 131072;
  int* rankp = (int*)base2;                       // NS*8192*4 = 512 KiB
  int* rcp = (int*)(base2 + 512 * 1024);          // 512 KiB
  u32* clist = (u32*)(base2 + 1024 * 1024);       // 80*512*4 = 160 KiB

  rank_decode_kernel<<<dim3(NBLK, NS), 256, 0, stream>>>(
      scores, class_ids, (const float4*)deltas, (const float2*)locs, stride_p,
      (float4*)boxes_out, bmax, flag, ccount, rankp, rcp);

  scatter_hazard_kernel<<<NBLK + 1, 256, 0, stream>>>(
      scores, class_ids, (const float4*)boxes_out, bmax, rankp, rcp, keys,
      bnms, clist, ccount, order_out, flag);

  nms_kernel<<<NCLASS + 1, 256, 0, stream>>>(clist, ccount, bnms, keys,
                                             keep_out, flag);
}

// Round 10
// 65.707 us; speedup vs baseline: 1.1304x; 1.1304x over previous
//
#include <hip/hip_runtime.h>

typedef unsigned long long u64;
typedef unsigned int u32;

#define NBOX 8192
#define NW64 128    // u64 words per fallback suppression bitmap
#define NCLASS 80
#define NCMAX 256   // fast-path class size cap; nc>NCMAX flags exact fallback
#define CHKCAP 256
#define NS 32       // rank slices
#define SLICE 256   // NBOX / NS
#define NBLK 32     // i-range blocks
#define K1GRID (NS * NBLK + 1)  // 1024 rank blocks + 1 hazard block
#define K2GRID (NBLK + NCLASS)  // 32 scatter + 80 class-NMS

// ---- monotone float<->uint mapping (order-preserving for all floats) ----
__device__ __forceinline__ u32 f32_mono(float f) {
  u32 u = __float_as_uint(f);
  return (u & 0x80000000u) ? ~u : (u | 0x80000000u);
}
__device__ __forceinline__ float mono_f32(u32 u) {
  u32 b = (u & 0x80000000u) ? (u ^ 0x80000000u) : ~u;
  return __uint_as_float(b);
}
__device__ __forceinline__ float readlane_f(float v, int l) {
  return __uint_as_float(__builtin_amdgcn_readlane(__float_as_uint(v), l));
}
// reduce 32-entry u32 array of block maxima, in-register
__device__ __forceinline__ u32 reduce_bmax(const u32* __restrict__ bmax, int t) {
  u32 bm = bmax[t & 31];
#pragma unroll
  for (int off = 16; off > 0; off >>= 1) {
    u32 o = __shfl_xor(bm, off);
    bm = (bm > o) ? bm : o;
  }
  return bm;
}

// NOTE (r7/r8 lesson): in-kernel grid barriers are a dead end on gfx950 —
// RMW-polling convoys the coherence point (~27us/barrier) and load-polling
// still needs __threadfence, whose buffer_wbl2/buffer_inv L2 walk costs
// ~20us/barrier. Kernel boundaries provide coherence cheaper. 3 plain nodes.

// ---- K1: u32 score-only rank partials + box decode/bmax (slice 0) +
// self-contained hazard check (block 1024, sole flag writer in K1).
// rank = #{score_j > score_i} + #{score_j == score_i && j < i}  (== stable
// position of i in argsort(-scores); exact JAX tie-break).
__global__ __launch_bounds__(256) void rank_decode_kernel(
    const float* __restrict__ scores, const int* __restrict__ class_ids,
    const float4* __restrict__ deltas, const float2* __restrict__ locs,
    const int* __restrict__ stride_p, float4* __restrict__ boxes_out,
    u32* __restrict__ bmax, int* __restrict__ flag, int* __restrict__ rankp) {
  const int t = threadIdx.x;
  const int b = blockIdx.x;

  if (b == NS * NBLK) {
    // ---- hazard block: recompute boxes + M locally (boxes_out is being
    // written concurrently by peer blocks — cannot read it). Adjacent-class
    // offset boxes can only overlap if one box hugs the top-right margin
    // (x2,y2 > M-65; x1,y1 >= -64 by construction) and the other the
    // bottom-left margin (x1,y1 < 1). Conservative IoU > 0.4 vs ref 0.5.
    __shared__ float4 bxA[CHKCAP], bxB[CHKCAP];
    __shared__ int clsA[CHKCAP], clsB[CHKCAP];
    __shared__ int na, nb, hitf;
    __shared__ u32 mred[4];
    if (t == 0) { na = 0; nb = 0; hitf = 0; }
    float s = (float)(*stride_p);
    u32 mymax = 0;
    for (int base = 0; base < NBOX; base += 256) {
      int i = base + t;
      float4 d = deltas[i];
      d.x = fmaxf(d.x, 0.f); d.y = fmaxf(d.y, 0.f);
      d.z = fmaxf(d.z, 0.f); d.w = fmaxf(d.w, 0.f);
      float2 c = locs[i];
      float x1 = c.x - s * d.x, y1 = c.y - s * d.y;
      float x2 = c.x + s * d.z, y2 = c.y + s * d.w;
      float m = fmaxf(fmaxf(x1, y1), fmaxf(x2, y2));
      u32 u = f32_mono(m);
      mymax = mymax > u ? mymax : u;
    }
#pragma unroll
    for (int off = 32; off > 0; off >>= 1) {
      u32 o = __shfl_xor(mymax, off);
      mymax = mymax > o ? mymax : o;
    }
    if ((t & 63) == 0) mred[t >> 6] = mymax;
    __syncthreads();  // mred ready; also orders na/nb init before atomics
    u32 g0 = mred[0] > mred[1] ? mred[0] : mred[1];
    u32 g1 = mred[2] > mred[3] ? mred[2] : mred[3];
    float M = mono_f32(g0 > g1 ? g0 : g1);  // fmax is order-exact
    float thrA = M - 65.0f;
    for (int base = 0; base < NBOX; base += 256) {
      int i = base + t;
      float4 d = deltas[i];
      d.x = fmaxf(d.x, 0.f); d.y = fmaxf(d.y, 0.f);
      d.z = fmaxf(d.z, 0.f); d.w = fmaxf(d.w, 0.f);
      float2 c = locs[i];
      float4 bb;
      bb.x = c.x - s * d.x; bb.y = c.y - s * d.y;
      bb.z = c.x + s * d.z; bb.w = c.y + s * d.w;
      int cls = class_ids[i];
      if (bb.z > thrA && bb.w > thrA) {
        int p = atomicAdd(&na, 1);
        if (p < CHKCAP) { bxA[p] = bb; clsA[p] = cls; }
      }
      if (bb.x < 1.0f && bb.y < 1.0f) {
        int p = atomicAdd(&nb, 1);
        if (p < CHKCAP) { bxB[p] = bb; clsB[p] = cls; }
      }
    }
    __syncthreads();
    int NA = na < CHKCAP ? na : CHKCAP;
    int NB = nb < CHKCAP ? nb : CHKCAP;
    bool hit = (t == 0) && (na > CHKCAP || nb > CHKCAP);
    for (int pr = t; pr < NA * NB; pr += 256) {
      int a = pr / NB, b2 = pr % NB;
      if (clsB[b2] != clsA[a] + 1) continue;
      float offa = (float)clsA[a] * (M + 1.0f);
      float offb = (float)clsB[b2] * (M + 1.0f);
      float4 A = bxA[a], Bb = bxB[b2];
      A.x += offa; A.y += offa; A.z += offa; A.w += offa;
      Bb.x += offb; Bb.y += offb; Bb.z += offb; Bb.w += offb;
      float ltx = fmaxf(A.x, Bb.x), lty = fmaxf(A.y, Bb.y);
      float rbx = fminf(A.z, Bb.z), rby = fminf(A.w, Bb.w);
      float ww = fmaxf(rbx - ltx, 0.f), hh = fmaxf(rby - lty, 0.f);
      float inter = ww * hh;
      float aa = (A.z - A.x) * (A.w - A.y);
      float ab = (Bb.z - Bb.x) * (Bb.w - Bb.y);
      float iou = inter / (aa + ab - inter);
      if (iou > 0.4f) hit = true;
    }
    if (hit) atomicOr(&hitf, 1);
    __syncthreads();
    if (t == 0) *flag = hitf;  // plain store; also clears stale flag per replay
    return;
  }

  // ---- rank blocks ----
  const int bi = b & 31;      // i-range
  const int slice = b >> 5;   // 0..31
  const int i = bi * 256 + t;

  __shared__ u32 st[SLICE];
  __shared__ u32 wmax[4];

  if (slice == 0) {  // decode boxes + per-block max (block-uniform branch)
    float s = (float)(*stride_p);
    float4 d = deltas[i];
    d.x = fmaxf(d.x, 0.f); d.y = fmaxf(d.y, 0.f);
    d.z = fmaxf(d.z, 0.f); d.w = fmaxf(d.w, 0.f);
    float2 c = locs[i];
    float4 bb;
    bb.x = c.x - s * d.x;
    bb.y = c.y - s * d.y;
    bb.z = c.x + s * d.z;
    bb.w = c.y + s * d.w;
    boxes_out[i] = bb;
    float m = fmaxf(fmaxf(bb.x, bb.y), fmaxf(bb.z, bb.w));
    u32 u = f32_mono(m);
#pragma unroll
    for (int off = 32; off > 0; off >>= 1) {
      u32 o = __shfl_xor(u, off);
      u = (u > o) ? u : o;
    }
    if ((t & 63) == 0) wmax[t >> 6] = u;
  }

  st[t] = f32_mono(scores[slice * 256 + t]);
  __syncthreads();
  if (slice == 0 && t == 0) {
    u32 m0 = wmax[0] > wmax[1] ? wmax[0] : wmax[1];
    u32 m1 = wmax[2] > wmax[3] ? wmax[2] : wmax[3];
    bmax[bi] = m0 > m1 ? m0 : m1;  // plain store
  }

  u32 mi = f32_mono(scores[i]);
  int tp = i - slice * 256;  // j<i  <=>  p<tp  (tp<0: none; tp>=256: all)
  int cnt = 0;
#pragma unroll 8
  for (int p = 0; p < SLICE; ++p) {
    u32 mj = st[p];  // wave-uniform LDS address -> broadcast
    bool less = (mj > mi) || (mj == mi && p < tp);
    cnt += less ? 1 : 0;
  }
  rankp[slice * NBOX + i] = cnt;
}

// ---- K2: scatter by rank (blocks 0..31) IN PARALLEL WITH per-class
// self-contained NMS (blocks 32..111). Class blocks gather + locally rank
// their own items, so they don't depend on the scatter — no barrier needed.
__global__ __launch_bounds__(256) void scatter_nms_kernel(
    const float* __restrict__ scores, const int* __restrict__ class_ids,
    const float4* __restrict__ boxes, const u32* __restrict__ bmax,
    const int* __restrict__ rankp, u64* __restrict__ keys,
    float4* __restrict__ bnms, float* __restrict__ order_out,
    float* __restrict__ keep_out, int* flag) {
  const int t = threadIdx.x;
  const int bid = blockIdx.x;

  if (bid < NBLK) {  // ---- scatter: order_out + fallback inputs ----
    int i = bid * 256 + t;
    int r = 0;
#pragma unroll
    for (int s2 = 0; s2 < NS; ++s2) r += rankp[s2 * NBOX + i];
    float maxc = mono_f32(reduce_bmax(bmax, t));
    u32 mi = f32_mono(scores[i]);
    keys[r] = ((u64)(~mi) << 32) | (u32)i;
    int cls = class_ids[i];
    float off = (float)cls * (maxc + 1.0f);
    float4 bb = boxes[i];
    bb.x += off; bb.y += off; bb.z += off; bb.w += off;
    bnms[r] = bb;
    order_out[r] = (float)i;
    return;
  }

  // ---- class NMS, self-contained ----
  const int c = bid - NBLK;
  if (*flag != 0) return;  // hazard set in K1 -> K3 fallback covers all
  __shared__ u64 ck[NCMAX];
  __shared__ u32 slist[NCMAX];
  __shared__ int cnt_s;
  if (t == 0) cnt_s = 0;
  __syncthreads();
  for (int base = 0; base < NBOX; base += 256) {
    int i2 = base + t;
    if (class_ids[i2] == c) {
      int p = atomicAdd(&cnt_s, 1);
      if (p < NCMAX) ck[p] = ((u64)(~f32_mono(scores[i2])) << 32) | (u32)i2;
    }
  }
  __syncthreads();
  int nc = cnt_s;
  if (nc > NCMAX) {  // ~9 sigma; K3 exact fallback handles it
    if (t == 0) atomicOr(flag, 1);
    return;
  }
  // local stable rank: ascending (~mono(score), idx) == (score desc, idx asc)
  if (t < nc) {
    u64 kme = ck[t];
    int r2 = 0;
    for (int p = 0; p < nc; ++p) r2 += (ck[p] < kme) ? 1 : 0;
    slist[r2] = (u32)kme;  // low 32 bits = original idx
  }
  __syncthreads();
  if (t >= 64) return;

  float maxc = mono_f32(reduce_bmax(bmax, t));
  float off = (float)c * (maxc + 1.0f);
  u32 L[4];
  float4 B[4];
#pragma unroll
  for (int d = 0; d < 4; ++d) {
    int j = d * 64 + t;
    L[d] = (j < nc) ? slist[j] : 0u;
    B[d] = boxes[L[d]];  // j>=nc -> harmless read of boxes[0]
    B[d].x += off; B[d].y += off; B[d].z += off; B[d].w += off;
  }
  u64 r0 = 0, r1 = 0, r2b = 0, r3 = 0;  // wave-uniform remv (SGPR)

#define CHUNK(CC, RC, PASSES)                                                  \
  {                                                                            \
    int lim = nc - CC * 64;                                                    \
    if (lim > 0) {                                                             \
      if (lim > 64) lim = 64;                                                  \
      for (int ii = 0; ii < lim; ++ii) {                                       \
        if (!((RC >> ii) & 1ull)) {                                            \
          float bix = readlane_f(B[CC].x, ii);                                 \
          float biy = readlane_f(B[CC].y, ii);                                 \
          float biz = readlane_f(B[CC].z, ii);                                 \
          float biw = readlane_f(B[CC].w, ii);                                 \
          float area_i = (biz - bix) * (biw - biy);                            \
          PASSES                                                               \
        }                                                                      \
      }                                                                        \
    }                                                                          \
  }
#define PASS(DD, RD, JGUARD)                                                   \
  {                                                                            \
    float4 bj = B[DD];                                                         \
    float ltx = fmaxf(bix, bj.x), lty = fmaxf(biy, bj.y);                      \
    float rbx = fminf(biz, bj.z), rby = fminf(biw, bj.w);                      \
    float ww = fmaxf(rbx - ltx, 0.f), hh = fmaxf(rby - lty, 0.f);              \
    float inter = ww * hh;                                                     \
    float area_j = (bj.z - bj.x) * (bj.w - bj.y);                              \
    float iou = inter / (area_i + area_j - inter);                             \
    int j = DD * 64 + t;                                                       \
    bool p = (iou > 0.5f) && (j < nc) && (JGUARD);                             \
    RD |= __ballot(p);                                                         \
  }

  CHUNK(0, r0, PASS(0, r0, t > ii) PASS(1, r1, true) PASS(2, r2b, true) PASS(3, r3, true))
  CHUNK(1, r1, PASS(1, r1, t > ii) PASS(2, r2b, true) PASS(3, r3, true))
  CHUNK(2, r2b, PASS(2, r2b, t > ii) PASS(3, r3, true))
  CHUNK(3, r3, PASS(3, r3, t > ii))
#undef PASS
#undef CHUNK

  u64 rr[4] = {r0, r1, r2b, r3};
#pragma unroll
  for (int d = 0; d < 4; ++d) {
    int j = d * 64 + t;
    if (j < nc) keep_out[L[d]] = ((rr[d] >> t) & 1ull) ? 0.0f : 1.0f;
  }
}

// ---- K3: exact single-block fallback (flag != 0 only; flag sources: K1
// hazard store, K2 overflow atomicOr — both finalized before this kernel).
__global__ __launch_bounds__(256) void fallback_kernel(
    const float4* __restrict__ bnms, const u64* __restrict__ keys,
    float* __restrict__ keep_out, const int* __restrict__ flag) {
  if (*flag == 0) return;
  __shared__ u64 remv[NW64];
  int t = threadIdx.x;
  for (int k = t; k < NW64; k += 256) remv[k] = 0;
  __syncthreads();
  if (t < 64) {
    int lane = t;
    for (int ii = 0; ii < NBOX; ++ii) {
      if ((remv[ii >> 6] >> (ii & 63)) & 1ull) continue;
      float4 bi = bnms[ii];
      float area_i = (bi.z - bi.x) * (bi.w - bi.y);
      for (int jb = ii + 1; jb < NBOX; jb += 64) {
        int j = jb + lane;
        bool p = false;
        if (j < NBOX) {
          float4 bj = bnms[j];
          float ltx = fmaxf(bi.x, bj.x), lty = fmaxf(bi.y, bj.y);
          float rbx = fminf(bi.z, bj.z), rby = fminf(bi.w, bj.w);
          float ww = fmaxf(rbx - ltx, 0.f), hh = fmaxf(rby - lty, 0.f);
          float inter = ww * hh;
          float area_j = (bj.z - bj.x) * (bj.w - bj.y);
          float iou = inter / (area_i + area_j - inter);
          p = iou > 0.5f;
        }
        u64 m = __ballot(p);
        if (lane == 0 && m) {
          int w0 = jb >> 6, sh = jb & 63;
          remv[w0] |= (m << sh);
          if (sh && (w0 + 1) < NW64) remv[w0 + 1] |= (m >> (64 - sh));
        }
      }
    }
  }
  __syncthreads();
  for (int k = t; k < NBOX; k += 256)
    keep_out[(u32)keys[k]] = ((remv[k >> 6] >> (k & 63)) & 1ull) ? 0.0f : 1.0f;
}

extern "C" void kernel_launch(void* const* d_in, const int* in_sizes, int n_in,
                              void* d_out, int out_size, void* d_ws, size_t ws_size,
                              hipStream_t stream) {
  const float* deltas = (const float*)d_in[0];
  const float* locs = (const float*)d_in[1];
  const float* scores = (const float*)d_in[2];
  const int* class_ids = (const int*)d_in[3];
  const int* stride_p = (const int*)d_in[4];

  float* boxes_out = (float*)d_out;                     // n*4 floats
  float* keep_out = (float*)d_out + (size_t)NBOX * 4;   // n floats (0/1)
  float* order_out = (float*)d_out + (size_t)NBOX * 5;  // n floats (indices)

  // workspace layout (all init done in-kernel; no memset nodes)
  u32* bmax = (u32*)((char*)d_ws + 64);           // 32*4 B, plain-stored
  int* flag = (int*)((char*)d_ws + 256);          // stored by K1 hazard block
  u64* keys = (u64*)((char*)d_ws + 4096);         // 64 KiB
  float4* bnms = (float4*)((char*)d_ws + 4096 + 65536);  // 128 KiB
  int* rankp = (int*)((char*)d_ws + 4096 + 65536 + 131072);  // NS*8192*4 = 1 MiB

  rank_decode_kernel<<<K1GRID, 256, 0, stream>>>(
      scores, class_ids, (const float4*)deltas, (const float2*)locs, stride_p,
      (float4*)boxes_out, bmax, flag, rankp);

  scatter_nms_kernel<<<K2GRID, 256, 0, stream>>>(
      scores, class_ids, (const float4*)boxes_out, bmax, rankp, keys, bnms,
      order_out, keep_out, flag);

  fallback_kernel<<<1, 256, 0, stream>>>(bnms, keys, keep_out, flag);
}

// Round 11
// 52.738 us; speedup vs baseline: 1.4084x; 1.2459x over previous
//
#include <hip/hip_runtime.h>

typedef unsigned long long u64;
typedef unsigned int u32;

#define NBOX 8192
#define NW64 128    // u64 words per fallback suppression bitmap
#define NCLASS 80
#define NCMAX 256   // fast-path class size cap; nc>NCMAX flags exact fallback
#define CHKCAP 256
#define NS 32       // rank slices
#define SLICE 256   // NBOX / NS
#define NBLK 32     // i-range blocks
#define K1GRID (NS * NBLK + 1)  // 1024 rank blocks + 1 hazard block
#define K2GRID (NBLK + NCLASS)  // 32 scatter + 80 class-NMS

// ---- monotone float<->uint mapping (order-preserving for all floats) ----
__device__ __forceinline__ u32 f32_mono(float f) {
  u32 u = __float_as_uint(f);
  return (u & 0x80000000u) ? ~u : (u | 0x80000000u);
}
__device__ __forceinline__ float mono_f32(u32 u) {
  u32 b = (u & 0x80000000u) ? (u ^ 0x80000000u) : ~u;
  return __uint_as_float(b);
}
__device__ __forceinline__ u64 readlane64(u64 v, int l) {
  u32 lo = __builtin_amdgcn_readlane((u32)v, l);
  u32 hi = __builtin_amdgcn_readlane((u32)(v >> 32), l);
  return ((u64)hi << 32) | (u64)lo;
}
// reduce 32-entry u32 array of block maxima, in-register
__device__ __forceinline__ u32 reduce_bmax(const u32* __restrict__ bmax, int t) {
  u32 bm = bmax[t & 31];
#pragma unroll
  for (int off = 16; off > 0; off >>= 1) {
    u32 o = __shfl_xor(bm, off);
    bm = (bm > o) ? bm : o;
  }
  return bm;
}

// NOTE (r7/r8): in-kernel grid barriers are a dead end on gfx950 (RMW-poll
// convoy ~27us/barrier; fence L2 walk ~20us/barrier). 3 plain nodes.
// NOTE (r10): the per-class SERIAL IoU loop (~102 rows x ~1000cy chain) was
// the hidden 46us floor across r4-r10. Fixed here by mask-then-scan:
// parallel all-pairs ballots (no loop-carried dep), then a bitmask-only
// serial scan (~30cy/row).

// ---- K1: u32 score-only rank partials + box decode/bmax (slice 0) +
// self-contained hazard check (block 1024, sole flag writer in K1).
// rank = #{score_j > score_i} + #{score_j == score_i && j < i}.
__global__ __launch_bounds__(256) void rank_decode_kernel(
    const float* __restrict__ scores, const int* __restrict__ class_ids,
    const float4* __restrict__ deltas, const float2* __restrict__ locs,
    const int* __restrict__ stride_p, float4* __restrict__ boxes_out,
    u32* __restrict__ bmax, int* __restrict__ flag, int* __restrict__ rankp) {
  const int t = threadIdx.x;
  const int b = blockIdx.x;

  if (b == NS * NBLK) {
    // hazard block: recompute boxes + M locally (boxes_out concurrent).
    // Adjacent-class offset boxes can only overlap if one hugs the top-right
    // margin (x2,y2 > M-65) and the other the bottom-left (x1,y1 < 1).
    // Conservative IoU > 0.4 vs ref 0.5.
    __shared__ float4 bxA[CHKCAP], bxB[CHKCAP];
    __shared__ int clsA[CHKCAP], clsB[CHKCAP];
    __shared__ int na, nb, hitf;
    __shared__ u32 mred[4];
    if (t == 0) { na = 0; nb = 0; hitf = 0; }
    float s = (float)(*stride_p);
    u32 mymax = 0;
    for (int base = 0; base < NBOX; base += 256) {
      int i = base + t;
      float4 d = deltas[i];
      d.x = fmaxf(d.x, 0.f); d.y = fmaxf(d.y, 0.f);
      d.z = fmaxf(d.z, 0.f); d.w = fmaxf(d.w, 0.f);
      float2 c = locs[i];
      float x1 = c.x - s * d.x, y1 = c.y - s * d.y;
      float x2 = c.x + s * d.z, y2 = c.y + s * d.w;
      float m = fmaxf(fmaxf(x1, y1), fmaxf(x2, y2));
      u32 u = f32_mono(m);
      mymax = mymax > u ? mymax : u;
    }
#pragma unroll
    for (int off = 32; off > 0; off >>= 1) {
      u32 o = __shfl_xor(mymax, off);
      mymax = mymax > o ? mymax : o;
    }
    if ((t & 63) == 0) mred[t >> 6] = mymax;
    __syncthreads();
    u32 g0 = mred[0] > mred[1] ? mred[0] : mred[1];
    u32 g1 = mred[2] > mred[3] ? mred[2] : mred[3];
    float M = mono_f32(g0 > g1 ? g0 : g1);
    float thrA = M - 65.0f;
    for (int base = 0; base < NBOX; base += 256) {
      int i = base + t;
      float4 d = deltas[i];
      d.x = fmaxf(d.x, 0.f); d.y = fmaxf(d.y, 0.f);
      d.z = fmaxf(d.z, 0.f); d.w = fmaxf(d.w, 0.f);
      float2 c = locs[i];
      float4 bb;
      bb.x = c.x - s * d.x; bb.y = c.y - s * d.y;
      bb.z = c.x + s * d.z; bb.w = c.y + s * d.w;
      int cls = class_ids[i];
      if (bb.z > thrA && bb.w > thrA) {
        int p = atomicAdd(&na, 1);
        if (p < CHKCAP) { bxA[p] = bb; clsA[p] = cls; }
      }
      if (bb.x < 1.0f && bb.y < 1.0f) {
        int p = atomicAdd(&nb, 1);
        if (p < CHKCAP) { bxB[p] = bb; clsB[p] = cls; }
      }
    }
    __syncthreads();
    int NA = na < CHKCAP ? na : CHKCAP;
    int NB = nb < CHKCAP ? nb : CHKCAP;
    bool hit = (t == 0) && (na > CHKCAP || nb > CHKCAP);
    for (int pr = t; pr < NA * NB; pr += 256) {
      int a = pr / NB, b2 = pr % NB;
      if (clsB[b2] != clsA[a] + 1) continue;
      float offa = (float)clsA[a] * (M + 1.0f);
      float offb = (float)clsB[b2] * (M + 1.0f);
      float4 A = bxA[a], Bb = bxB[b2];
      A.x += offa; A.y += offa; A.z += offa; A.w += offa;
      Bb.x += offb; Bb.y += offb; Bb.z += offb; Bb.w += offb;
      float ltx = fmaxf(A.x, Bb.x), lty = fmaxf(A.y, Bb.y);
      float rbx = fminf(A.z, Bb.z), rby = fminf(A.w, Bb.w);
      float ww = fmaxf(rbx - ltx, 0.f), hh = fmaxf(rby - lty, 0.f);
      float inter = ww * hh;
      float aa = (A.z - A.x) * (A.w - A.y);
      float ab = (Bb.z - Bb.x) * (Bb.w - Bb.y);
      float iou = inter / (aa + ab - inter);
      if (iou > 0.4f) hit = true;
    }
    if (hit) atomicOr(&hitf, 1);
    __syncthreads();
    if (t == 0) *flag = hitf;  // plain store; clears stale flag per replay
    return;
  }

  // ---- rank blocks ----
  const int bi = b & 31;
  const int slice = b >> 5;
  const int i = bi * 256 + t;

  __shared__ u32 st[SLICE];
  __shared__ u32 wmax[4];

  if (slice == 0) {  // decode boxes + per-block max
    float s = (float)(*stride_p);
    float4 d = deltas[i];
    d.x = fmaxf(d.x, 0.f); d.y = fmaxf(d.y, 0.f);
    d.z = fmaxf(d.z, 0.f); d.w = fmaxf(d.w, 0.f);
    float2 c = locs[i];
    float4 bb;
    bb.x = c.x - s * d.x;
    bb.y = c.y - s * d.y;
    bb.z = c.x + s * d.z;
    bb.w = c.y + s * d.w;
    boxes_out[i] = bb;
    float m = fmaxf(fmaxf(bb.x, bb.y), fmaxf(bb.z, bb.w));
    u32 u = f32_mono(m);
#pragma unroll
    for (int off = 32; off > 0; off >>= 1) {
      u32 o = __shfl_xor(u, off);
      u = (u > o) ? u : o;
    }
    if ((t & 63) == 0) wmax[t >> 6] = u;
  }

  st[t] = f32_mono(scores[slice * 256 + t]);
  __syncthreads();
  if (slice == 0 && t == 0) {
    u32 m0 = wmax[0] > wmax[1] ? wmax[0] : wmax[1];
    u32 m1 = wmax[2] > wmax[3] ? wmax[2] : wmax[3];
    bmax[bi] = m0 > m1 ? m0 : m1;
  }

  u32 mi = f32_mono(scores[i]);
  int tp = i - slice * 256;
  int cnt = 0;
#pragma unroll 8
  for (int p = 0; p < SLICE; ++p) {
    u32 mj = st[p];
    bool less = (mj > mi) || (mj == mi && p < tp);
    cnt += less ? 1 : 0;
  }
  rankp[slice * NBOX + i] = cnt;
}

// ---- K2: scatter (blocks 0..31) in parallel with per-class mask+scan NMS
// (blocks 32..111). Class blocks are self-contained (gather + local rank).
__global__ __launch_bounds__(256) void scatter_nms_kernel(
    const float* __restrict__ scores, const int* __restrict__ class_ids,
    const float4* __restrict__ boxes, const u32* __restrict__ bmax,
    const int* __restrict__ rankp, u64* __restrict__ keys,
    float4* __restrict__ bnms, float* __restrict__ order_out,
    float* __restrict__ keep_out, int* flag) {
  const int t = threadIdx.x;
  const int bid = blockIdx.x;

  if (bid < NBLK) {  // ---- scatter: order_out + fallback inputs ----
    int i = bid * 256 + t;
    int r = 0;
#pragma unroll
    for (int s2 = 0; s2 < NS; ++s2) r += rankp[s2 * NBOX + i];
    float maxc = mono_f32(reduce_bmax(bmax, t));
    u32 mi = f32_mono(scores[i]);
    keys[r] = ((u64)(~mi) << 32) | (u32)i;
    int cls = class_ids[i];
    float off = (float)cls * (maxc + 1.0f);
    float4 bb = boxes[i];
    bb.x += off; bb.y += off; bb.z += off; bb.w += off;
    bnms[r] = bb;
    order_out[r] = (float)i;
    return;
  }

  // ---- class NMS: gather -> local rank -> parallel mask -> scalar scan ----
  const int c = bid - NBLK;
  if (*flag != 0) return;  // K1 hazard -> K3 fallback covers everything
  __shared__ u64 ck[NCMAX];
  __shared__ u32 slist[NCMAX];
  __shared__ float4 bx[NCMAX];
  __shared__ u64 smask[NCMAX][4];
  __shared__ int cnt_s;
  if (t == 0) cnt_s = 0;
  __syncthreads();

  {  // gather, software-prefetched one stride ahead
    int nxtc = class_ids[t];
    float nxts = scores[t];
    for (int base = 0; base < NBOX; base += 256) {
      int cur = nxtc;
      float cs = nxts;
      if (base + 256 < NBOX) {
        nxtc = class_ids[base + 256 + t];
        nxts = scores[base + 256 + t];
      }
      if (cur == c) {
        int p = atomicAdd(&cnt_s, 1);
        if (p < NCMAX) ck[p] = ((u64)(~f32_mono(cs)) << 32) | (u32)(base + t);
      }
    }
  }
  __syncthreads();
  int nc = cnt_s;
  if (nc > NCMAX) {  // ~9 sigma; K3 exact fallback handles it
    if (t == 0) atomicOr(flag, 1);
    return;
  }
  // local stable rank: ascending (~mono(score), idx) == (score desc, idx asc)
  if (t < nc) {
    u64 kme = ck[t];
    int r2 = 0;
    for (int p = 0; p < nc; ++p) r2 += (ck[p] < kme) ? 1 : 0;
    slist[r2] = (u32)kme;  // low 32 = original idx
  }
  __syncthreads();

  float maxc = mono_f32(reduce_bmax(bmax, t));
  float off = (float)c * (maxc + 1.0f);
  for (int k = t; k < nc; k += 256) {
    float4 bb = boxes[slist[k]];
    bb.x += off; bb.y += off; bb.z += off; bb.w += off;
    bx[k] = bb;
  }
  __syncthreads();

  // parallel mask build: row i handled by wave (i&3); one ballot per 64-j
  // word; no loop-carried dependency -> ballots pipeline at issue rate.
  {
    const int wv = t >> 6;
    const int lane = t & 63;
    const int nw = (nc + 63) >> 6;
    for (int i = wv; i < nc; i += 4) {
      float4 bi = bx[i];  // uniform LDS address -> broadcast
      float area_i = (bi.z - bi.x) * (bi.w - bi.y);
      for (int w = 0; w < nw; ++w) {
        int j2 = w * 64 + lane;
        float4 bj = bx[j2 < NCMAX ? j2 : 0];
        float ltx = fmaxf(bi.x, bj.x), lty = fmaxf(bi.y, bj.y);
        float rbx = fminf(bi.z, bj.z), rby = fminf(bi.w, bj.w);
        float ww = fmaxf(rbx - ltx, 0.f), hh = fmaxf(rby - lty, 0.f);
        float inter = ww * hh;
        float area_j = (bj.z - bj.x) * (bj.w - bj.y);
        float iou = inter / (area_i + area_j - inter);
        bool p = (iou > 0.5f) && (j2 > i) && (j2 < nc);
        u64 mm = __ballot(p);
        if (lane == 0) smask[i][w] = mm;
      }
    }
  }
  __syncthreads();
  if (t >= 64) return;

  // wave 0: bitmask-only greedy scan. Lane l holds mask rows l, l+64,
  // l+128, l+192 (4 words each, static register indexing). remv R0..R3 and
  // keep bits K0..K3 are wave-uniform scalars. Per row: scalar bit test,
  // branchless sm = 0-kb, 8 readlanes + 4 and/or — ~30cy, no IoU in chain.
  u64 ma[4], mb[4], mc[4], md[4];
#pragma unroll
  for (int w = 0; w < 4; ++w) {
    ma[w] = smask[t][w];
    mb[w] = smask[64 + t][w];
    mc[w] = smask[128 + t][w];
    md[w] = smask[192 + t][w];
  }
  u64 R0 = 0, R1 = 0, R2 = 0, R3 = 0;
  u64 K0 = 0, K1 = 0, K2 = 0, K3 = 0;

#define SCAND(D, MD, RD, KD)                                                   \
  {                                                                            \
    int lim = nc - (D) * 64;                                                   \
    if (lim > 0) {                                                             \
      if (lim > 64) lim = 64;                                                  \
      for (int ii = 0; ii < lim; ++ii) {                                       \
        u64 kb = ((RD >> ii) & 1ull) ^ 1ull;                                   \
        KD |= kb << ii;                                                        \
        u64 sm2 = 0ull - kb;                                                   \
        R0 |= readlane64(MD[0], ii) & sm2;                                     \
        R1 |= readlane64(MD[1], ii) & sm2;                                     \
        R2 |= readlane64(MD[2], ii) & sm2;                                     \
        R3 |= readlane64(MD[3], ii) & sm2;                                     \
      }                                                                        \
    }                                                                          \
  }
  SCAND(0, ma, R0, K0)
  SCAND(1, mb, R1, K1)
  SCAND(2, mc, R2, K2)
  SCAND(3, md, R3, K3)
#undef SCAND

  u64 kk[4] = {K0, K1, K2, K3};
#pragma unroll
  for (int d = 0; d < 4; ++d) {
    int j = d * 64 + t;
    if (j < nc) keep_out[slist[j]] = ((kk[d] >> t) & 1ull) ? 1.0f : 0.0f;
  }
}

// ---- K3: exact single-block fallback (flag != 0 only).
__global__ __launch_bounds__(256) void fallback_kernel(
    const float4* __restrict__ bnms, const u64* __restrict__ keys,
    float* __restrict__ keep_out, const int* __restrict__ flag) {
  if (*flag == 0) return;
  __shared__ u64 remv[NW64];
  int t = threadIdx.x;
  for (int k = t; k < NW64; k += 256) remv[k] = 0;
  __syncthreads();
  if (t < 64) {
    int lane = t;
    for (int ii = 0; ii < NBOX; ++ii) {
      if ((remv[ii >> 6] >> (ii & 63)) & 1ull) continue;
      float4 bi = bnms[ii];
      float area_i = (bi.z - bi.x) * (bi.w - bi.y);
      for (int jb = ii + 1; jb < NBOX; jb += 64) {
        int j = jb + lane;
        bool p = false;
        if (j < NBOX) {
          float4 bj = bnms[j];
          float ltx = fmaxf(bi.x, bj.x), lty = fmaxf(bi.y, bj.y);
          float rbx = fminf(bi.z, bj.z), rby = fminf(bi.w, bj.w);
          float ww = fmaxf(rbx - ltx, 0.f), hh = fmaxf(rby - lty, 0.f);
          float inter = ww * hh;
          float area_j = (bj.z - bj.x) * (bj.w - bj.y);
          float iou = inter / (area_i + area_j - inter);
          p = iou > 0.5f;
        }
        u64 m = __ballot(p);
        if (lane == 0 && m) {
          int w0 = jb >> 6, sh = jb & 63;
          remv[w0] |= (m << sh);
          if (sh && (w0 + 1) < NW64) remv[w0 + 1] |= (m >> (64 - sh));
        }
      }
    }
  }
  __syncthreads();
  for (int k = t; k < NBOX; k += 256)
    keep_out[(u32)keys[k]] = ((remv[k >> 6] >> (k & 63)) & 1ull) ? 0.0f : 1.0f;
}

extern "C" void kernel_launch(void* const* d_in, const int* in_sizes, int n_in,
                              void* d_out, int out_size, void* d_ws, size_t ws_size,
                              hipStream_t stream) {
  const float* deltas = (const float*)d_in[0];
  const float* locs = (const float*)d_in[1];
  const float* scores = (const float*)d_in[2];
  const int* class_ids = (const int*)d_in[3];
  const int* stride_p = (const int*)d_in[4];

  float* boxes_out = (float*)d_out;                     // n*4 floats
  float* keep_out = (float*)d_out + (size_t)NBOX * 4;   // n floats (0/1)
  float* order_out = (float*)d_out + (size_t)NBOX * 5;  // n floats (indices)

  // workspace layout (all init in-kernel; no memset nodes)
  u32* bmax = (u32*)((char*)d_ws + 64);           // 32*4 B, plain-stored
  int* flag = (int*)((char*)d_ws + 256);          // stored by K1 hazard block
  u64* keys = (u64*)((char*)d_ws + 4096);         // 64 KiB
  float4* bnms = (float4*)((char*)d_ws + 4096 + 65536);  // 128 KiB
  int* rankp = (int*)((char*)d_ws + 4096 + 65536 + 131072);  // 1 MiB

  rank_decode_kernel<<<K1GRID, 256, 0, stream>>>(
      scores, class_ids, (const float4*)deltas, (const float2*)locs, stride_p,
      (float4*)boxes_out, bmax, flag, rankp);

  scatter_nms_kernel<<<K2GRID, 256, 0, stream>>>(
      scores, class_ids, (const float4*)boxes_out, bmax, rankp, keys, bnms,
      order_out, keep_out, flag);

  fallback_kernel<<<1, 256, 0, stream>>>(bnms, keys, keep_out, flag);
}

// Round 12
// 51.971 us; speedup vs baseline: 1.4292x; 1.0147x over previous
//
#include <hip/hip_runtime.h>

typedef unsigned long long u64;
typedef unsigned int u32;

#define NBOX 8192
#define NW64 128    // u64 words per fallback suppression bitmap
#define NCLASS 80
#define NCMAX 256   // fast-path class size cap; nc>NCMAX flags exact fallback
#define CHKCAP 256
#define NS 32       // rank slices
#define SLICE 256   // NBOX / NS
#define NBLK 32     // i-range blocks
#define K1GRID (NS * NBLK + 1)        // 1024 rank blocks + 1 hazard block
#define K2GRID (NBLK + NCLASS + 1)    // 32 scatter + 80 class-NMS + 1 fallback

// ---- monotone float<->uint mapping (order-preserving for all floats) ----
__device__ __forceinline__ u32 f32_mono(float f) {
  u32 u = __float_as_uint(f);
  return (u & 0x80000000u) ? ~u : (u | 0x80000000u);
}
__device__ __forceinline__ float mono_f32(u32 u) {
  u32 b = (u & 0x80000000u) ? (u ^ 0x80000000u) : ~u;
  return __uint_as_float(b);
}
__device__ __forceinline__ u64 readlane64(u64 v, int l) {
  u32 lo = __builtin_amdgcn_readlane((u32)v, l);
  u32 hi = __builtin_amdgcn_readlane((u32)(v >> 32), l);
  return ((u64)hi << 32) | (u64)lo;
}
// reduce 32-entry u32 array of block maxima, in-register
__device__ __forceinline__ u32 reduce_bmax(const u32* __restrict__ bmax, int t) {
  u32 bm = bmax[t & 31];
#pragma unroll
  for (int off = 16; off > 0; off >>= 1) {
    u32 o = __shfl_xor(bm, off);
    bm = (bm > o) ? bm : o;
  }
  return bm;
}

// NOTE (r7/r8): in-kernel grid barriers are a dead end on gfx950 (RMW-poll
// convoy ~27us/barrier; fence L2 walk ~20us/barrier). Plain kernel nodes.
// NOTE (r10/r11): serial per-class IoU loop was a hidden ~46us floor; fixed
// by mask-then-scan. NOTE (r11): remaining cost is ~12us per graph node ->
// this round: 3 nodes -> 2 by finalizing ALL flag sources in K1 (hazard
// block also histograms classes for the overflow check).

// ---- K1: u32 score-only rank partials + box decode/bmax (slice 0) +
// self-contained hazard/overflow check (block 1024 = sole flag writer).
// rank = #{score_j > score_i} + #{score_j == score_i && j < i}.
__global__ __launch_bounds__(256) void rank_decode_kernel(
    const float* __restrict__ scores, const int* __restrict__ class_ids,
    const float4* __restrict__ deltas, const float2* __restrict__ locs,
    const int* __restrict__ stride_p, float4* __restrict__ boxes_out,
    u32* __restrict__ bmax, int* __restrict__ flag, int* __restrict__ rankp) {
  const int t = threadIdx.x;
  const int b = blockIdx.x;

  if (b == NS * NBLK) {
    // hazard block: recompute boxes + M locally (boxes_out concurrent).
    // (a) cross-class geometric hazard: adjacent-class offset boxes can only
    //     overlap if one hugs the top-right margin (x2,y2 > M-65) and the
    //     other the bottom-left (x1,y1 < 1); conservative IoU > 0.4 vs 0.5.
    // (b) class-size overflow: any class with > NCMAX members.
    // Either condition -> flag=1 -> K2 fallback block recomputes everything.
    __shared__ float4 bxA[CHKCAP], bxB[CHKCAP];
    __shared__ int clsA[CHKCAP], clsB[CHKCAP];
    __shared__ int hist[NCLASS];
    __shared__ int na, nb, hitf;
    __shared__ u32 mred[4];
    if (t == 0) { na = 0; nb = 0; hitf = 0; }
    if (t < NCLASS) hist[t] = 0;
    float s = (float)(*stride_p);
    u32 mymax = 0;
    for (int base = 0; base < NBOX; base += 256) {
      int i = base + t;
      float4 d = deltas[i];
      d.x = fmaxf(d.x, 0.f); d.y = fmaxf(d.y, 0.f);
      d.z = fmaxf(d.z, 0.f); d.w = fmaxf(d.w, 0.f);
      float2 c = locs[i];
      float x1 = c.x - s * d.x, y1 = c.y - s * d.y;
      float x2 = c.x + s * d.z, y2 = c.y + s * d.w;
      float m = fmaxf(fmaxf(x1, y1), fmaxf(x2, y2));
      u32 u = f32_mono(m);
      mymax = mymax > u ? mymax : u;
    }
#pragma unroll
    for (int off = 32; off > 0; off >>= 1) {
      u32 o = __shfl_xor(mymax, off);
      mymax = mymax > o ? mymax : o;
    }
    if ((t & 63) == 0) mred[t >> 6] = mymax;
    __syncthreads();  // mred/hist/na/nb ready
    u32 g0 = mred[0] > mred[1] ? mred[0] : mred[1];
    u32 g1 = mred[2] > mred[3] ? mred[2] : mred[3];
    float M = mono_f32(g0 > g1 ? g0 : g1);  // max is order-exact
    float thrA = M - 65.0f;
    for (int base = 0; base < NBOX; base += 256) {
      int i = base + t;
      float4 d = deltas[i];
      d.x = fmaxf(d.x, 0.f); d.y = fmaxf(d.y, 0.f);
      d.z = fmaxf(d.z, 0.f); d.w = fmaxf(d.w, 0.f);
      float2 c = locs[i];
      float4 bb;
      bb.x = c.x - s * d.x; bb.y = c.y - s * d.y;
      bb.z = c.x + s * d.z; bb.w = c.y + s * d.w;
      int cls = class_ids[i];
      atomicAdd(&hist[cls], 1);
      if (bb.z > thrA && bb.w > thrA) {
        int p = atomicAdd(&na, 1);
        if (p < CHKCAP) { bxA[p] = bb; clsA[p] = cls; }
      }
      if (bb.x < 1.0f && bb.y < 1.0f) {
        int p = atomicAdd(&nb, 1);
        if (p < CHKCAP) { bxB[p] = bb; clsB[p] = cls; }
      }
    }
    __syncthreads();
    if (t < NCLASS && hist[t] > NCMAX) atomicOr(&hitf, 1);
    int NA = na < CHKCAP ? na : CHKCAP;
    int NB = nb < CHKCAP ? nb : CHKCAP;
    bool hit = (t == 0) && (na > CHKCAP || nb > CHKCAP);
    for (int pr = t; pr < NA * NB; pr += 256) {
      int a = pr / NB, b2 = pr % NB;
      if (clsB[b2] != clsA[a] + 1) continue;
      float offa = (float)clsA[a] * (M + 1.0f);
      float offb = (float)clsB[b2] * (M + 1.0f);
      float4 A = bxA[a], Bb = bxB[b2];
      A.x += offa; A.y += offa; A.z += offa; A.w += offa;
      Bb.x += offb; Bb.y += offb; Bb.z += offb; Bb.w += offb;
      float ltx = fmaxf(A.x, Bb.x), lty = fmaxf(A.y, Bb.y);
      float rbx = fminf(A.z, Bb.z), rby = fminf(A.w, Bb.w);
      float ww = fmaxf(rbx - ltx, 0.f), hh = fmaxf(rby - lty, 0.f);
      float inter = ww * hh;
      float aa = (A.z - A.x) * (A.w - A.y);
      float ab = (Bb.z - Bb.x) * (Bb.w - Bb.y);
      float iou = inter / (aa + ab - inter);
      if (iou > 0.4f) hit = true;
    }
    if (hit) atomicOr(&hitf, 1);
    __syncthreads();
    if (t == 0) *flag = hitf;  // sole writer; plain store clears stale value
    return;
  }

  // ---- rank blocks ----
  const int bi = b & 31;
  const int slice = b >> 5;
  const int i = bi * 256 + t;

  __shared__ u32 st[SLICE];
  __shared__ u32 wmax[4];

  if (slice == 0) {  // decode boxes + per-block max
    float s = (float)(*stride_p);
    float4 d = deltas[i];
    d.x = fmaxf(d.x, 0.f); d.y = fmaxf(d.y, 0.f);
    d.z = fmaxf(d.z, 0.f); d.w = fmaxf(d.w, 0.f);
    float2 c = locs[i];
    float4 bb;
    bb.x = c.x - s * d.x;
    bb.y = c.y - s * d.y;
    bb.z = c.x + s * d.z;
    bb.w = c.y + s * d.w;
    boxes_out[i] = bb;
    float m = fmaxf(fmaxf(bb.x, bb.y), fmaxf(bb.z, bb.w));
    u32 u = f32_mono(m);
#pragma unroll
    for (int off = 32; off > 0; off >>= 1) {
      u32 o = __shfl_xor(u, off);
      u = (u > o) ? u : o;
    }
    if ((t & 63) == 0) wmax[t >> 6] = u;
  }

  st[t] = f32_mono(scores[slice * 256 + t]);
  __syncthreads();
  if (slice == 0 && t == 0) {
    u32 m0 = wmax[0] > wmax[1] ? wmax[0] : wmax[1];
    u32 m1 = wmax[2] > wmax[3] ? wmax[2] : wmax[3];
    bmax[bi] = m0 > m1 ? m0 : m1;
  }

  u32 mi = f32_mono(scores[i]);
  int tp = i - slice * 256;
  int cnt = 0;
#pragma unroll 8
  for (int p = 0; p < SLICE; ++p) {
    u32 mj = st[p];
    bool less = (mj > mi) || (mj == mi && p < tp);
    cnt += less ? 1 : 0;
  }
  rankp[slice * NBOX + i] = cnt;
}

// ---- K2: scatter (0..31) || class mask+scan NMS (32..111) || exact
// fallback (block 112; self-contained, reads only K1-finalized data).
// flag is finalized in K1, so keep_out is written by class blocks XOR the
// fallback block — no intra-kernel race anywhere.
__global__ __launch_bounds__(256) void scatter_nms_kernel(
    const float* __restrict__ scores, const int* __restrict__ class_ids,
    const float4* __restrict__ boxes, const u32* __restrict__ bmax,
    const int* __restrict__ rankp, u64* __restrict__ keys,
    float4* __restrict__ bnms, float* __restrict__ order_out,
    float* __restrict__ keep_out, const int* __restrict__ flag) {
  const int t = threadIdx.x;
  const int bid = blockIdx.x;

  __shared__ u64 ck[NCMAX];
  __shared__ u32 slist[NCMAX];
  __shared__ float4 bx[NCMAX];
  __shared__ u64 smask[NCMAX][4];
  __shared__ int cnt_s;
  __shared__ u32 perm[NBOX];   // fallback only (32 KiB)
  __shared__ u64 remv[NW64];   // fallback only

  if (bid < NBLK) {  // ---- scatter: order_out + fallback-input arrays ----
    int i = bid * 256 + t;
    int r = 0;
#pragma unroll
    for (int s2 = 0; s2 < NS; ++s2) r += rankp[s2 * NBOX + i];
    float maxc = mono_f32(reduce_bmax(bmax, t));
    u32 mi = f32_mono(scores[i]);
    keys[r] = ((u64)(~mi) << 32) | (u32)i;
    int cls = class_ids[i];
    float off = (float)cls * (maxc + 1.0f);
    float4 bb = boxes[i];
    bb.x += off; bb.y += off; bb.z += off; bb.w += off;
    bnms[r] = bb;
    order_out[r] = (float)i;
    return;
  }

  if (bid < NBLK + NCLASS) {
    // ---- class NMS: gather -> local rank -> parallel mask -> scalar scan --
    const int c = bid - NBLK;
    if (*flag != 0) return;  // fallback block covers everything
    if (t == 0) cnt_s = 0;
    __syncthreads();

    {  // gather, software-prefetched one stride ahead
      int nxtc = class_ids[t];
      float nxts = scores[t];
      for (int base = 0; base < NBOX; base += 256) {
        int cur = nxtc;
        float cs = nxts;
        if (base + 256 < NBOX) {
          nxtc = class_ids[base + 256 + t];
          nxts = scores[base + 256 + t];
        }
        if (cur == c) {
          int p = atomicAdd(&cnt_s, 1);
          if (p < NCMAX) ck[p] = ((u64)(~f32_mono(cs)) << 32) | (u32)(base + t);
        }
      }
    }
    __syncthreads();
    int nc = cnt_s;
    if (nc > NCMAX) return;  // defensive; K1 histogram already set flag
    // local stable rank: ascending (~mono(score), idx) == (score desc, idx)
    if (t < nc) {
      u64 kme = ck[t];
      int r2 = 0;
      for (int p = 0; p < nc; ++p) r2 += (ck[p] < kme) ? 1 : 0;
      slist[r2] = (u32)kme;  // low 32 = original idx
    }
    __syncthreads();

    float maxc = mono_f32(reduce_bmax(bmax, t));
    float off = (float)c * (maxc + 1.0f);
    for (int k = t; k < nc; k += 256) {
      float4 bb = boxes[slist[k]];
      bb.x += off; bb.y += off; bb.z += off; bb.w += off;
      bx[k] = bb;
    }
    __syncthreads();

    // parallel mask build: row i by wave (i&3); one ballot per 64-j word.
    {
      const int wv = t >> 6;
      const int lane = t & 63;
      const int nw = (nc + 63) >> 6;
      for (int i = wv; i < nc; i += 4) {
        float4 bi = bx[i];  // uniform LDS address -> broadcast
        float area_i = (bi.z - bi.x) * (bi.w - bi.y);
        for (int w = 0; w < nw; ++w) {
          int j2 = w * 64 + lane;
          float4 bj = bx[j2 < NCMAX ? j2 : 0];
          float ltx = fmaxf(bi.x, bj.x), lty = fmaxf(bi.y, bj.y);
          float rbx = fminf(bi.z, bj.z), rby = fminf(bi.w, bj.w);
          float ww = fmaxf(rbx - ltx, 0.f), hh = fmaxf(rby - lty, 0.f);
          float inter = ww * hh;
          float area_j = (bj.z - bj.x) * (bj.w - bj.y);
          float iou = inter / (area_i + area_j - inter);
          bool p = (iou > 0.5f) && (j2 > i) && (j2 < nc);
          u64 mm = __ballot(p);
          if (lane == 0) smask[i][w] = mm;
        }
      }
    }
    __syncthreads();
    if (t >= 64) return;

    // wave 0: bitmask-only greedy scan (no IoU in the serial chain).
    u64 ma[4], mb[4], mc[4], md[4];
#pragma unroll
    for (int w = 0; w < 4; ++w) {
      ma[w] = smask[t][w];
      mb[w] = smask[64 + t][w];
      mc[w] = smask[128 + t][w];
      md[w] = smask[192 + t][w];
    }
    u64 R0 = 0, R1 = 0, R2 = 0, R3 = 0;
    u64 K0 = 0, K1 = 0, K2 = 0, K3 = 0;

#define SCAND(D, MD, RD, KD)                                                   \
  {                                                                            \
    int lim = nc - (D) * 64;                                                   \
    if (lim > 0) {                                                             \
      if (lim > 64) lim = 64;                                                  \
      for (int ii = 0; ii < lim; ++ii) {                                       \
        u64 kb = ((RD >> ii) & 1ull) ^ 1ull;                                   \
        KD |= kb << ii;                                                        \
        u64 sm2 = 0ull - kb;                                                   \
        R0 |= readlane64(MD[0], ii) & sm2;                                     \
        R1 |= readlane64(MD[1], ii) & sm2;                                     \
        R2 |= readlane64(MD[2], ii) & sm2;                                     \
        R3 |= readlane64(MD[3], ii) & sm2;                                     \
      }                                                                        \
    }                                                                          \
  }
    SCAND(0, ma, R0, K0)
    SCAND(1, mb, R1, K1)
    SCAND(2, mc, R2, K2)
    SCAND(3, md, R3, K3)
#undef SCAND

    u64 kk[4] = {K0, K1, K2, K3};
#pragma unroll
    for (int d = 0; d < 4; ++d) {
      int j = d * 64 + t;
      if (j < nc) keep_out[slist[j]] = ((kk[d] >> t) & 1ull) ? 1.0f : 0.0f;
    }
    return;
  }

  // ---- block 112: exact fallback (flag != 0 only; never on this data).
  // Self-contained: rebuilds the sorted permutation from rankp (finalized in
  // K1) and computes boxes on the fly — does NOT touch keys/bnms, which peer
  // scatter blocks are writing concurrently.
  if (*flag == 0) return;
  for (int k = t; k < NW64; k += 256) remv[k] = 0;
  for (int i = t; i < NBOX; i += 256) {
    int r = 0;
#pragma unroll
    for (int s2 = 0; s2 < NS; ++s2) r += rankp[s2 * NBOX + i];
    perm[r] = (u32)i;
  }
  __syncthreads();
  float maxc = mono_f32(reduce_bmax(bmax, t));
  if (t < 64) {
    int lane = t;
    for (int ii = 0; ii < NBOX; ++ii) {
      if ((remv[ii >> 6] >> (ii & 63)) & 1ull) continue;
      u32 pi = perm[ii];
      float offi = (float)class_ids[pi] * (maxc + 1.0f);
      float4 bi = boxes[pi];
      bi.x += offi; bi.y += offi; bi.z += offi; bi.w += offi;
      float area_i = (bi.z - bi.x) * (bi.w - bi.y);
      for (int jb = ii + 1; jb < NBOX; jb += 64) {
        int j = jb + lane;
        bool p = false;
        if (j < NBOX) {
          u32 pj = perm[j];
          float offj = (float)class_ids[pj] * (maxc + 1.0f);
          float4 bj = boxes[pj];
          bj.x += offj; bj.y += offj; bj.z += offj; bj.w += offj;
          float ltx = fmaxf(bi.x, bj.x), lty = fmaxf(bi.y, bj.y);
          float rbx = fminf(bi.z, bj.z), rby = fminf(bi.w, bj.w);
          float ww = fmaxf(rbx - ltx, 0.f), hh = fmaxf(rby - lty, 0.f);
          float inter = ww * hh;
          float area_j = (bj.z - bj.x) * (bj.w - bj.y);
          float iou = inter / (area_i + area_j - inter);
          p = iou > 0.5f;
        }
        u64 m = __ballot(p);
        if (lane == 0 && m) {
          int w0 = jb >> 6, sh = jb & 63;
          remv[w0] |= (m << sh);
          if (sh && (w0 + 1) < NW64) remv[w0 + 1] |= (m >> (64 - sh));
        }
      }
    }
  }
  __syncthreads();
  for (int k = t; k < NBOX; k += 256)
    keep_out[perm[k]] = ((remv[k >> 6] >> (k & 63)) & 1ull) ? 0.0f : 1.0f;
}

extern "C" void kernel_launch(void* const* d_in, const int* in_sizes, int n_in,
                              void* d_out, int out_size, void* d_ws, size_t ws_size,
                              hipStream_t stream) {
  const float* deltas = (const float*)d_in[0];
  const float* locs = (const float*)d_in[1];
  const float* scores = (const float*)d_in[2];
  const int* class_ids = (const int*)d_in[3];
  const int* stride_p = (const int*)d_in[4];

  float* boxes_out = (float*)d_out;                     // n*4 floats
  float* keep_out = (float*)d_out + (size_t)NBOX * 4;   // n floats (0/1)
  float* order_out = (float*)d_out + (size_t)NBOX * 5;  // n floats (indices)

  // workspace layout (all init in-kernel; no memset nodes)
  u32* bmax = (u32*)((char*)d_ws + 64);           // 32*4 B, plain-stored
  int* flag = (int*)((char*)d_ws + 256);          // stored by K1 hazard block
  u64* keys = (u64*)((char*)d_ws + 4096);         // 64 KiB
  float4* bnms = (float4*)((char*)d_ws + 4096 + 65536);  // 128 KiB
  int* rankp = (int*)((char*)d_ws + 4096 + 65536 + 131072);  // 1 MiB

  rank_decode_kernel<<<K1GRID, 256, 0, stream>>>(
      scores, class_ids, (const float4*)deltas, (const float2*)locs, stride_p,
      (float4*)boxes_out, bmax, flag, rankp);

  scatter_nms_kernel<<<K2GRID, 256, 0, stream>>>(
      scores, class_ids, (const float4*)boxes_out, bmax, rankp, keys, bnms,
      order_out, keep_out, flag);
}